// Round 1
// baseline (789.215 us; speedup 1.0000x reference)
//
#include <hip/hip_runtime.h>
#include <math.h>

#define HH 300
#define WW 300
#define CC 4
#define MM 4096
#define MT 32   // samples (m) per block
#define PP 8    // h-row partitions per block

__global__ void zero_out_kernel(float* out) { out[0] = 0.0f; }

__global__ __launch_bounds__(256) void nufft_loss_kernel(
    const float* __restrict__ img,     // H*W           (img_pred, last dim 1)
    const float* __restrict__ kdata,   // C*M*2
    const float* __restrict__ omega,   // 2*M
    const float* __restrict__ csm,     // C*H*W*2
    float* __restrict__ out)
{
    const int tid  = threadIdx.x;
    const int mloc = tid & (MT - 1);
    const int p    = tid >> 5;                 // 0..7
    const int c    = blockIdx.y;
    const int m    = blockIdx.x * MT + mloc;

    const float TWO_PI = 6.283185307179586f;
    const float om0 = omega[m];        // y/H-dim frequency
    const float om1 = omega[MM + m];   // z/W-dim frequency

    // ez(w) = exp(-2i*pi*om1*(w-150)); start at w=0 -> exp(+2i*pi*om1*150), step exp(-2i*pi*om1)
    float ez0r, ez0i, szr, szi;
    __sincosf(TWO_PI * om1 * 150.0f, &ez0i, &ez0r);
    __sincosf(-TWO_PI * om1, &szi, &szr);
    // ey(h) = exp(-2i*pi*om0*(h-150)); start at h=p, step over h+=8
    float eyr, eyi, syr, syi;
    __sincosf(-TWO_PI * om0 * (float)(p - 150), &eyi, &eyr);
    __sincosf(-TWO_PI * om0 * 8.0f, &syi, &syr);

    float accr = 0.0f, acci = 0.0f;

    for (int h = p; h < HH; h += PP) {
        const float4* crow = (const float4*)(csm + (size_t)(c * HH + h) * WW * 2);
        const float2* irow = (const float2*)(img + (size_t)h * WW);
        float cr = ez0r, ci = ez0i;       // current ez
        float inr = 0.0f, ini = 0.0f;     // inner sum over w
        #pragma unroll 2
        for (int w2 = 0; w2 < WW / 2; ++w2) {
            float4 cs = crow[w2];         // csm[w], csm[w+1] (re,im,re,im)
            float2 iv = irow[w2];         // img[w], img[w+1]
            // w even
            float sr = cs.x * iv.x, si = cs.y * iv.x;
            inr = fmaf(sr, cr, fmaf(-si, ci, inr));
            ini = fmaf(sr, ci, fmaf( si, cr, ini));
            float nr = cr * szr - ci * szi;   // ez at w+1
            float ni = cr * szi + ci * szr;
            // w odd
            sr = cs.z * iv.y; si = cs.w * iv.y;
            inr = fmaf(sr, nr, fmaf(-si, ni, inr));
            ini = fmaf(sr, ni, fmaf( si, nr, ini));
            cr = nr * szr - ni * szi;         // ez at w+2
            ci = nr * szi + ni * szr;
        }
        // acc += inner * ey(h)
        accr = fmaf(inr, eyr, fmaf(-ini, eyi, accr));
        acci = fmaf(inr, eyi, fmaf( ini, eyr, acci));
        // advance ey by 8 rows
        float tr = eyr * syr - eyi * syi;
        eyi = eyr * syi + eyi * syr;
        eyr = tr;
    }

    __shared__ float redr[256], redi[256];
    redr[tid] = accr;
    redi[tid] = acci;
    __syncthreads();

    if (tid < 64) {
        float val = 0.0f;
        if (tid < MT) {
            float kr = 0.0f, ki = 0.0f;
            #pragma unroll
            for (int q = 0; q < PP; ++q) { kr += redr[tid + q * MT]; ki += redi[tid + q * MT]; }
            kr *= (1.0f / 300.0f);   // 1/sqrt(H*W)
            ki *= (1.0f / 300.0f);
            const size_t kidx = ((size_t)c * MM + m) * 2;
            const float kdr = kdata[kidx];
            const float kdi = kdata[kidx + 1];
            const float w0 = om0 * TWO_PI, w1 = om1 * TWO_PI;
            const float wg = sqrtf(w0 * w0 + w1 * w1) + 1.0f;
            const float dr = wg * (kr - kdr);
            const float di = wg * (ki - kdi);
            val = (dr * dr + di * di) * (1.0f / (2.0f * CC * MM));
        }
        // full-wave (64-lane) down reduction; lanes 32..63 contribute 0
        #pragma unroll
        for (int off = 32; off > 0; off >>= 1) val += __shfl_down(val, off);
        if (tid == 0) atomicAdd(out, val);
    }
}

extern "C" void kernel_launch(void* const* d_in, const int* in_sizes, int n_in,
                              void* d_out, int out_size, void* d_ws, size_t ws_size,
                              hipStream_t stream) {
    const float* img   = (const float*)d_in[0];   // (300,300,1)
    const float* kdata = (const float*)d_in[1];   // (1,4,4096,2)
    const float* omega = (const float*)d_in[2];   // (1,2,4096)
    // d_in[3] all_dcomp: unused by the reference loss
    const float* csm   = (const float*)d_in[4];   // (4,300,300,2)
    float* out = (float*)d_out;

    zero_out_kernel<<<1, 1, 0, stream>>>(out);
    dim3 grid(MM / MT, CC);
    nufft_loss_kernel<<<grid, 256, 0, stream>>>(img, kdata, omega, csm, out);
}

// Round 2
// 133.555 us; speedup vs baseline: 5.9093x; 5.9093x over previous
//
#include <hip/hip_runtime.h>
#include <math.h>

#define HH 300
#define WW 300
#define CC 4
#define MM 4096
#define KP 640    // padded K = 2*W=600 -> 640
#define MP 1280   // padded rows = C*H=1200 -> 1280
#define NP 8192   // 2*M (real | imag output columns)
#define BK 32

typedef __attribute__((ext_vector_type(4))) float f32x4;
typedef __attribute__((ext_vector_type(8))) short short8;
typedef const __attribute__((address_space(1))) void g_void;
typedef __attribute__((address_space(3))) void l_void;

__device__ __forceinline__ ushort f2b(float f) {
    unsigned x = __float_as_uint(f);
    return (ushort)((x + 0x7fffu + ((x >> 16) & 1u)) >> 16);
}
__device__ __forceinline__ float b2f(ushort u) {
    return __uint_as_float(((unsigned)u) << 16);
}

__global__ void zero_out_kernel(float* out) { out[0] = 0.0f; }

// A = [sim_r | sim_i] : MP x KP bf16, row = c*300+h, k<300 -> sim_r[w=k], 300<=k<600 -> sim_i
__global__ __launch_bounds__(256) void prep_a_kernel(
    const float* __restrict__ img, const float* __restrict__ csm, ushort* __restrict__ Aws)
{
    int idx = blockIdx.x * 256 + threadIdx.x;      // 0 .. MP*KP-1
    int row = idx / KP;
    int k   = idx - row * KP;
    float v = 0.0f;
    if (row < CC * HH && k < 2 * WW) {
        int c = row / HH;
        int h = row - c * HH;
        int w = (k < WW) ? k : k - WW;
        float im = img[h * WW + w];
        const float* cs = csm + (((size_t)c * HH + h) * WW + w) * 2;
        v = ((k < WW) ? cs[0] : cs[1]) * im;
    }
    Aws[idx] = f2b(v);
}

// B^T : NP x KP bf16 (n-major, k contiguous).
// n<4096 (real col, m=n):  k<300 -> ez_r,  300<=k<600 -> -ez_i
// n>=4096 (imag col):      k<300 -> ez_i,  300<=k<600 ->  ez_r
// ez = exp(-2i*pi*om1*(w-150)) -> ez_r=cos(th), ez_i=-sin(th), th=2pi*om1*(w-150)
__global__ __launch_bounds__(256) void prep_b_kernel(
    const float* __restrict__ omega, ushort* __restrict__ Bws)
{
    int idx = blockIdx.x * 256 + threadIdx.x;      // 0 .. NP*KP-1
    int n = idx / KP;
    int k = idx - n * KP;
    float v = 0.0f;
    if (k < 2 * WW) {
        int m = n & (MM - 1);
        int part = n >> 12;                        // 0=real col, 1=imag col
        int w = (k < WW) ? k : k - WW;
        float om1 = omega[MM + m];
        float th = 6.283185307179586f * om1 * (float)(w - 150);
        float s, c;
        __sincosf(th, &s, &c);
        float ezr = c, ezi = -s;
        if (part == 0) v = (k < WW) ? ezr : -ezi;
        else           v = (k < WW) ? ezi :  ezr;
    }
    Bws[idx] = f2b(v);
}

// C(MP x NP, bf16) = A(MP x KP) * B^T(NP x KP)^T  -- m97-style 128x128 tile, BK=32
__global__ __launch_bounds__(256) void gemm_kernel(
    const ushort* __restrict__ A, const ushort* __restrict__ B, ushort* __restrict__ C)
{
    __shared__ ushort As[128 * BK];
    __shared__ ushort Bs[128 * BK];

    const int t    = threadIdx.x;
    const int wave = t >> 6;           // wave-uniform
    const int ln   = t & 63;
    const int row0 = blockIdx.y * 128;
    const int col0 = blockIdx.x * 128;
    const int wr = wave >> 1, wc = wave & 1;
    const int lr = ln & 15;            // row/col within 16x16
    const int lq = ln >> 4;            // quad 0..3

    // staging: pass p covers rows p*64..p*64+63; thread t -> row r0a, k-seg ks0 (8 bf16 = 16B)
    const int flat0 = t * 16;          // bytes within 4KB pass
    const int r0a = flat0 >> 6;        // 0..63  (64 B per row)
    const int ks0 = (flat0 >> 4) & 3;  // 0..3

    f32x4 acc[4][4] = {};

    for (int k0 = 0; k0 < KP; k0 += BK) {
        const ushort* gA0 = A + (size_t)(row0 + r0a) * KP + k0 + ks0 * 8;
        const ushort* gA1 = A + (size_t)(row0 + 64 + r0a) * KP + k0 + ks0 * 8;
        const ushort* gB0 = B + (size_t)(col0 + r0a) * KP + k0 + ks0 * 8;
        const ushort* gB1 = B + (size_t)(col0 + 64 + r0a) * KP + k0 + ks0 * 8;
        __builtin_amdgcn_global_load_lds((g_void*)gA0, (l_void*)(As + wave * 512), 16, 0, 0);
        __builtin_amdgcn_global_load_lds((g_void*)gA1, (l_void*)(As + 2048 + wave * 512), 16, 0, 0);
        __builtin_amdgcn_global_load_lds((g_void*)gB0, (l_void*)(Bs + wave * 512), 16, 0, 0);
        __builtin_amdgcn_global_load_lds((g_void*)gB1, (l_void*)(Bs + 2048 + wave * 512), 16, 0, 0);
        __syncthreads();   // drains vmcnt before barrier

        short8 a[4], b[4];
        #pragma unroll
        for (int i = 0; i < 4; ++i)
            a[i] = *(const short8*)(As + (wr * 64 + i * 16 + lr) * BK + lq * 8);
        #pragma unroll
        for (int j = 0; j < 4; ++j)
            b[j] = *(const short8*)(Bs + (wc * 64 + j * 16 + lr) * BK + lq * 8);
        #pragma unroll
        for (int i = 0; i < 4; ++i)
            #pragma unroll
            for (int j = 0; j < 4; ++j)
                acc[i][j] = __builtin_amdgcn_mfma_f32_16x16x32_bf16(a[i], b[j], acc[i][j], 0, 0, 0);
        __syncthreads();
    }

    // C/D layout: col = ln&15, row = (ln>>4)*4 + reg
    #pragma unroll
    for (int i = 0; i < 4; ++i) {
        #pragma unroll
        for (int j = 0; j < 4; ++j) {
            #pragma unroll
            for (int r = 0; r < 4; ++r) {
                int row = row0 + wr * 64 + i * 16 + lq * 4 + r;
                int col = col0 + wc * 64 + j * 16 + lr;
                if (row < CC * HH)
                    C[(size_t)row * NP + col] = f2b(acc[i][j][r]);
            }
        }
    }
}

// k[c,m] = (1/300) * sum_h tmp[c,h,m] * ey[m,h];  loss terms
__global__ __launch_bounds__(256) void reduce_kernel(
    const ushort* __restrict__ Ctmp, const float* __restrict__ kdata,
    const float* __restrict__ omega, float* __restrict__ out)
{
    const int t = blockIdx.x * 256 + threadIdx.x;  // 0..16383
    const int c = t >> 12;
    const int m = t & (MM - 1);

    const float TWO_PI = 6.283185307179586f;
    const float om0 = omega[m];
    const float om1 = omega[MM + m];

    // ey(h) = exp(-2pi i om0 (h-150)); h=0: exp(+i*2pi*om0*150)
    float eyr, eyi, scr, ssi;
    __sincosf(TWO_PI * om0 * 150.0f, &eyi, &eyr);
    __sincosf(-TWO_PI * om0, &ssi, &scr);

    float kr = 0.0f, ki = 0.0f;
    const ushort* basep = Ctmp + (size_t)(c * HH) * NP + m;
    #pragma unroll 4
    for (int h = 0; h < HH; ++h) {
        float tr = b2f(basep[(size_t)h * NP]);
        float ti = b2f(basep[(size_t)h * NP + MM]);
        kr = fmaf(tr, eyr, fmaf(-ti, eyi, kr));
        ki = fmaf(tr, eyi, fmaf( ti, eyr, ki));
        float nr = eyr * scr - eyi * ssi;
        eyi = eyr * ssi + eyi * scr;
        eyr = nr;
    }
    kr *= (1.0f / 300.0f);
    ki *= (1.0f / 300.0f);

    const size_t kidx = ((size_t)c * MM + m) * 2;
    const float kdr = kdata[kidx];
    const float kdi = kdata[kidx + 1];
    const float w0 = om0 * TWO_PI, w1 = om1 * TWO_PI;
    const float wg = sqrtf(w0 * w0 + w1 * w1) + 1.0f;
    const float dr = wg * (kr - kdr);
    const float di = wg * (ki - kdi);
    float val = (dr * dr + di * di) * (1.0f / (2.0f * CC * MM));

    #pragma unroll
    for (int off = 32; off > 0; off >>= 1) val += __shfl_down(val, off);
    if ((threadIdx.x & 63) == 0) atomicAdd(out, val);
}

extern "C" void kernel_launch(void* const* d_in, const int* in_sizes, int n_in,
                              void* d_out, int out_size, void* d_ws, size_t ws_size,
                              hipStream_t stream) {
    const float* img   = (const float*)d_in[0];   // (300,300,1)
    const float* kdata = (const float*)d_in[1];   // (1,4,4096,2)
    const float* omega = (const float*)d_in[2];   // (1,2,4096)
    const float* csm   = (const float*)d_in[4];   // (4,300,300,2)
    float* out = (float*)d_out;

    ushort* Aws = (ushort*)d_ws;                              // MP*KP*2  = 1.64 MB
    ushort* Bws = (ushort*)((char*)d_ws + (2u << 20));        // NP*KP*2  = 10.5 MB
    ushort* Ctmp = (ushort*)((char*)d_ws + (13u << 20));      // MP*NP*2  = 21.0 MB (ends ~34 MB)

    zero_out_kernel<<<1, 1, 0, stream>>>(out);
    prep_a_kernel<<<(MP * KP) / 256, 256, 0, stream>>>(img, csm, Aws);
    prep_b_kernel<<<(NP * KP) / 256, 256, 0, stream>>>(omega, Bws);
    gemm_kernel<<<dim3(NP / 128, MP / 128), 256, 0, stream>>>(Aws, Bws, Ctmp);
    reduce_kernel<<<(CC * MM) / 256, 256, 0, stream>>>(Ctmp, kdata, omega, out);
}

// Round 3
// 105.331 us; speedup vs baseline: 7.4927x; 1.2680x over previous
//
#include <hip/hip_runtime.h>
#include <math.h>

#define HH 300
#define WW 300
#define CC 4
#define MM 4096
#define KP 640          // padded K = 2*W=600 -> 640
#define CSTRIDE 384     // per-coil row stride (3*128: every 128-row tile is coil-pure)
#define MP (CC*CSTRIDE) // 1536
#define NP 8192         // 2*M (real | imag output columns)
#define BK 32
#define NRB (MP/128)    // 12 row-blocks

typedef __attribute__((ext_vector_type(4))) float f32x4;
typedef __attribute__((ext_vector_type(8))) short short8;
typedef const __attribute__((address_space(1))) void g_void;
typedef __attribute__((address_space(3))) void l_void;

#define TWO_PI 6.283185307179586f

__device__ __forceinline__ ushort f2b(float f) {
    unsigned x = __float_as_uint(f);
    return (ushort)((x + 0x7fffu + ((x >> 16) & 1u)) >> 16);
}

// One prep kernel: zero out[0], build A = [sim_r | sim_i] (MP x KP, coil stride 384),
// build B^T (NP x KP): n<4096 real col {ez_r | -ez_i}, n>=4096 imag col {ez_i | ez_r}
__global__ __launch_bounds__(256) void prep_kernel(
    const float* __restrict__ img, const float* __restrict__ csm,
    const float* __restrict__ omega, ushort* __restrict__ A,
    ushort* __restrict__ B, float* __restrict__ out)
{
    const int bid = blockIdx.x;
    if (bid == 0 && threadIdx.x == 0) out[0] = 0.0f;
    const int ABLK = (MP * KP) / 256;   // 3840
    if (bid < ABLK) {
        int idx = bid * 256 + threadIdx.x;
        int row = idx / KP;
        int k   = idx - row * KP;
        int c = row / CSTRIDE;
        int h = row - c * CSTRIDE;
        float v = 0.0f;
        if (h < HH && k < 2 * WW) {
            int w = (k < WW) ? k : k - WW;
            float im = img[h * WW + w];
            const float* cs = csm + (((size_t)c * HH + h) * WW + w) * 2;
            v = ((k < WW) ? cs[0] : cs[1]) * im;
        }
        A[idx] = f2b(v);
    } else {
        int idx = (bid - ABLK) * 256 + threadIdx.x;   // 0 .. NP*KP-1
        int n = idx / KP;
        int k = idx - n * KP;
        float v = 0.0f;
        if (k < 2 * WW) {
            int m = n & (MM - 1);
            int part = n >> 12;
            int w = (k < WW) ? k : k - WW;
            float om1 = omega[MM + m];
            float th = TWO_PI * om1 * (float)(w - 150);
            float s, c;
            __sincosf(th, &s, &c);
            float ezr = c, ezi = -s;
            v = (part == 0) ? ((k < WW) ? ezr : -ezi) : ((k < WW) ? ezi : ezr);
        }
        B[idx] = f2b(v);
    }
}

// GEMM (128x128 tile, BK=32, global_load_lds w16) with fused ey-rotation epilogue:
// P[rb][col] = sum over the 128 rows (h) in this row-block of acc * ey(m,h)
// where ey = exp(-2pi i om0 (h-150)), stored as float2 (sum*eyr, sum*eyi).
__global__ __launch_bounds__(256) void gemm_kernel(
    const ushort* __restrict__ A, const ushort* __restrict__ B,
    const float* __restrict__ omega, float2* __restrict__ P)
{
    __shared__ ushort As[128 * BK];
    __shared__ ushort Bs[128 * BK];
    __shared__ float2 red[128];

    const int t    = threadIdx.x;
    const int wave = t >> 6;
    const int ln   = t & 63;
    const int row0 = blockIdx.y * 128;
    const int col0 = blockIdx.x * 128;
    const int wr = wave >> 1, wc = wave & 1;
    const int lr = ln & 15;
    const int lq = ln >> 4;

    const int flat0 = t * 16;
    const int r0a = flat0 >> 6;
    const int ks0 = (flat0 >> 4) & 3;

    f32x4 acc[4][4] = {};

    for (int k0 = 0; k0 < KP; k0 += BK) {
        const ushort* gA0 = A + (size_t)(row0 + r0a) * KP + k0 + ks0 * 8;
        const ushort* gA1 = A + (size_t)(row0 + 64 + r0a) * KP + k0 + ks0 * 8;
        const ushort* gB0 = B + (size_t)(col0 + r0a) * KP + k0 + ks0 * 8;
        const ushort* gB1 = B + (size_t)(col0 + 64 + r0a) * KP + k0 + ks0 * 8;
        __builtin_amdgcn_global_load_lds((g_void*)gA0, (l_void*)(As + wave * 512), 16, 0, 0);
        __builtin_amdgcn_global_load_lds((g_void*)gA1, (l_void*)(As + 2048 + wave * 512), 16, 0, 0);
        __builtin_amdgcn_global_load_lds((g_void*)gB0, (l_void*)(Bs + wave * 512), 16, 0, 0);
        __builtin_amdgcn_global_load_lds((g_void*)gB1, (l_void*)(Bs + 2048 + wave * 512), 16, 0, 0);
        __syncthreads();

        short8 a[4], b[4];
        #pragma unroll
        for (int i = 0; i < 4; ++i)
            a[i] = *(const short8*)(As + (wr * 64 + i * 16 + lr) * BK + lq * 8);
        #pragma unroll
        for (int j = 0; j < 4; ++j)
            b[j] = *(const short8*)(Bs + (wc * 64 + j * 16 + lr) * BK + lq * 8);
        #pragma unroll
        for (int i = 0; i < 4; ++i)
            #pragma unroll
            for (int j = 0; j < 4; ++j)
                acc[i][j] = __builtin_amdgcn_mfma_f32_16x16x32_bf16(a[i], b[j], acc[i][j], 0, 0, 0);
        __syncthreads();
    }

    // ---- fused stage-2 epilogue ----
    if (t < 128) red[t] = make_float2(0.0f, 0.0f);
    __syncthreads();

    const int c  = row0 / CSTRIDE;        // block-uniform (CSTRIDE = 3*128)
    const int h0 = row0 - c * CSTRIDE;

    #pragma unroll
    for (int j = 0; j < 4; ++j) {
        const int jcol = wc * 64 + j * 16 + lr;      // 0..127
        const int m = (col0 + jcol) & (MM - 1);
        const float om0 = omega[m];
        // step = exp(-2pi i om0)
        float ss, sc;
        __sincosf(TWO_PI * om0, &ss, &sc);
        const float str = sc, sti = -ss;
        float pr = 0.0f, pi = 0.0f;
        #pragma unroll
        for (int i = 0; i < 4; ++i) {
            const int hb = h0 + wr * 64 + i * 16 + lq * 4;
            float sn, cs;
            __sincosf(TWO_PI * om0 * (float)(hb - 150), &sn, &cs);
            float er = cs, ei = -sn;      // ey at h = hb
            #pragma unroll
            for (int r = 0; r < 4; ++r) {
                const float v = acc[i][j][r];
                pr = fmaf(v, er, pr);
                pi = fmaf(v, ei, pi);
                float nr = er * str - ei * sti;   // advance h by 1
                ei = er * sti + ei * str;
                er = nr;
            }
        }
        atomicAdd(&red[jcol].x, pr);
        atomicAdd(&red[jcol].y, pi);
    }
    __syncthreads();

    if (t < 128) {
        const int rb = row0 >> 7;
        P[(size_t)rb * NP + col0 + t] = red[t];
    }
}

// loss: k[c,m] from 3 row-block partials (real cols at m, imag cols at m+4096)
__global__ __launch_bounds__(256) void loss_kernel(
    const float2* __restrict__ P, const float* __restrict__ kdata,
    const float* __restrict__ omega, float* __restrict__ out)
{
    const int t = blockIdx.x * 256 + threadIdx.x;  // 0..16383
    const int c = t >> 12;
    const int m = t & (MM - 1);

    float kr = 0.0f, ki = 0.0f;
    #pragma unroll
    for (int q = 0; q < 3; ++q) {
        const int rb = 3 * c + q;
        float2 p0 = P[(size_t)rb * NP + m];          // real-col partial
        float2 p1 = P[(size_t)rb * NP + m + MM];     // imag-col partial
        kr += p0.x - p1.y;
        ki += p0.y + p1.x;
    }
    kr *= (1.0f / 300.0f);
    ki *= (1.0f / 300.0f);

    const float om0 = omega[m];
    const float om1 = omega[MM + m];
    const size_t kidx = ((size_t)c * MM + m) * 2;
    const float kdr = kdata[kidx];
    const float kdi = kdata[kidx + 1];
    const float w0 = om0 * TWO_PI, w1 = om1 * TWO_PI;
    const float wg = sqrtf(w0 * w0 + w1 * w1) + 1.0f;
    const float dr = wg * (kr - kdr);
    const float di = wg * (ki - kdi);
    float val = (dr * dr + di * di) * (1.0f / (2.0f * CC * MM));

    #pragma unroll
    for (int off = 32; off > 0; off >>= 1) val += __shfl_down(val, off);
    if ((threadIdx.x & 63) == 0) atomicAdd(out, val);
}

extern "C" void kernel_launch(void* const* d_in, const int* in_sizes, int n_in,
                              void* d_out, int out_size, void* d_ws, size_t ws_size,
                              hipStream_t stream) {
    const float* img   = (const float*)d_in[0];   // (300,300,1)
    const float* kdata = (const float*)d_in[1];   // (1,4,4096,2)
    const float* omega = (const float*)d_in[2];   // (1,2,4096)
    const float* csm   = (const float*)d_in[4];   // (4,300,300,2)
    float* out = (float*)d_out;

    ushort* Aws = (ushort*)d_ws;                              // MP*KP*2  = 1.97 MB
    ushort* Bws = (ushort*)((char*)d_ws + (2u << 20));        // NP*KP*2  = 10.5 MB
    float2* Pws = (float2*)((char*)d_ws + (13u << 20));       // NRB*NP*8 = 786 KB

    const int ablk = (MP * KP) / 256;         // 3840
    const int bblk = (NP * KP) / 256;         // 20480
    prep_kernel<<<ablk + bblk, 256, 0, stream>>>(img, csm, omega, Aws, Bws, out);
    gemm_kernel<<<dim3(NP / 128, MP / 128), 256, 0, stream>>>(Aws, Bws, omega, Pws);
    loss_kernel<<<(CC * MM) / 256, 256, 0, stream>>>(Pws, kdata, omega, out);
}

// Round 4
// 91.564 us; speedup vs baseline: 8.6192x; 1.1503x over previous
//
#include <hip/hip_runtime.h>
#include <math.h>

#define HH 300
#define WW 300
#define CC 4
#define MM 4096
#define KP 640          // padded K (fp8: 640 bytes/row), 2*W=600 -> 640
#define CSTRIDE 384     // per-coil row stride (3*128: every 128-row tile coil-pure)
#define MP (CC*CSTRIDE) // 1536
#define NP 8192         // 2*M (real | imag output columns)
#define BK 128          // K-chunk per iteration (one mfma_scale per 16x16 tile)
#define NRB (MP/128)    // 12 row-blocks

typedef __attribute__((ext_vector_type(4))) float f32x4;
typedef __attribute__((ext_vector_type(4))) int int4v;
typedef __attribute__((ext_vector_type(8))) int int8v;
typedef const __attribute__((address_space(1))) void g_void;
typedef __attribute__((address_space(3))) void l_void;

#define TWO_PI 6.283185307179586f

// A value at (row, k): row = c*CSTRIDE + h; k<300 -> sim_r[w=k]; 300<=k<600 -> sim_i; else 0
__device__ __forceinline__ float aval(const float* img, const float* csm,
                                      int c, int h, int k) {
    if (k >= 2 * WW) return 0.0f;
    int w = (k < WW) ? k : k - WW;
    float im = img[h * WW + w];
    const float* cs = csm + (((size_t)c * HH + h) * WW + w) * 2;
    return ((k < WW) ? cs[0] : cs[1]) * im;
}

// B^T value at (n, k): n<4096 real col {ez_r | -ez_i}, n>=4096 imag col {ez_i | ez_r}
__device__ __forceinline__ float bval(const float* omega, int n, int k) {
    if (k >= 2 * WW) return 0.0f;
    int m = n & (MM - 1);
    int part = n >> 12;
    int w = (k < WW) ? k : k - WW;
    float om1 = omega[MM + m];
    float s, c;
    __sincosf(TWO_PI * om1 * (float)(w - 150), &s, &c);
    float ezr = c, ezi = -s;
    return (part == 0) ? ((k < WW) ? ezr : -ezi) : ((k < WW) ? ezi : ezr);
}

// prep: zero out[0], build A (MP x KP fp8 e4m3) and B^T (NP x KP fp8), 2 elems/thread
__global__ __launch_bounds__(256) void prep_kernel(
    const float* __restrict__ img, const float* __restrict__ csm,
    const float* __restrict__ omega, ushort* __restrict__ A,
    ushort* __restrict__ B, float* __restrict__ out)
{
    const int bid = blockIdx.x;
    if (bid == 0 && threadIdx.x == 0) out[0] = 0.0f;
    const int ABLK = (MP * KP / 2) / 256;   // 1920
    if (bid < ABLK) {
        int idx = bid * 256 + threadIdx.x;            // pair index
        int row = idx / (KP / 2);
        int k   = (idx - row * (KP / 2)) * 2;
        int c = row / CSTRIDE;
        int h = row - c * CSTRIDE;
        float v0 = 0.0f, v1 = 0.0f;
        if (h < HH) { v0 = aval(img, csm, c, h, k); v1 = aval(img, csm, c, h, k + 1); }
        int pk = __builtin_amdgcn_cvt_pk_fp8_f32(v0, v1, 0, false);
        A[idx] = (ushort)pk;
    } else {
        int idx = (bid - ABLK) * 256 + threadIdx.x;   // 0 .. NP*KP/2-1
        int n = idx / (KP / 2);
        int k = (idx - n * (KP / 2)) * 2;
        float v0 = bval(omega, n, k);
        float v1 = bval(omega, n, k + 1);
        int pk = __builtin_amdgcn_cvt_pk_fp8_f32(v0, v1, 0, false);
        B[idx] = (ushort)pk;
    }
}

// fp8 MX GEMM (128x128 tile, BK=128, unit scales) + fused ey-rotation epilogue.
__global__ __launch_bounds__(256) void gemm_kernel(
    const unsigned char* __restrict__ A, const unsigned char* __restrict__ B,
    const float* __restrict__ omega, float2* __restrict__ P)
{
    __shared__ unsigned char As[128 * BK];
    __shared__ unsigned char Bs[128 * BK];
    __shared__ float2 red[128];

    const int t    = threadIdx.x;
    const int wave = t >> 6;
    const int ln   = t & 63;
    const int row0 = blockIdx.y * 128;
    const int col0 = blockIdx.x * 128;
    const int wr = wave >> 1, wc = wave & 1;
    const int lr = ln & 15;
    const int lq = ln >> 4;

    if (t < 128) red[t] = make_float2(0.0f, 0.0f);

    // staging: pass p covers rows p*32..p*32+31 (128 B/row). thread t -> row srow,
    // physical 32B chunk cphys, 16B half. XOR swizzle: phys chunk c holds logical
    // chunk c ^ (row&3)  -> fragment ds_read_b128 becomes 2-way (free).
    const int srow  = t >> 3;
    const int cphys = (t >> 1) & 3;
    const int half  = t & 1;
    const int sgoff = ((cphys ^ (srow & 3)) << 5) + (half << 4);

    f32x4 acc[4][4] = {};

    for (int k0 = 0; k0 < KP; k0 += BK) {
        #pragma unroll
        for (int p = 0; p < 4; ++p) {
            const unsigned char* gA = A + (size_t)(row0 + p * 32 + srow) * KP + k0 + sgoff;
            const unsigned char* gB = B + (size_t)(col0 + p * 32 + srow) * KP + k0 + sgoff;
            __builtin_amdgcn_global_load_lds((g_void*)gA, (l_void*)(As + p * 4096 + t * 16), 16, 0, 0);
            __builtin_amdgcn_global_load_lds((g_void*)gB, (l_void*)(Bs + p * 4096 + t * 16), 16, 0, 0);
        }
        __syncthreads();

        int8v a[4], b[4];
        #pragma unroll
        for (int i = 0; i < 4; ++i) {
            const int r = wr * 64 + i * 16 + lr;
            const unsigned char* pA = As + r * BK + ((lq ^ (lr & 3)) << 5);
            int4v lo = *(const int4v*)pA;
            int4v hi = *(const int4v*)(pA + 16);
            a[i] = __builtin_shufflevector(lo, hi, 0, 1, 2, 3, 4, 5, 6, 7);
        }
        #pragma unroll
        for (int j = 0; j < 4; ++j) {
            const int r = wc * 64 + j * 16 + lr;
            const unsigned char* pB = Bs + r * BK + ((lq ^ (lr & 3)) << 5);
            int4v lo = *(const int4v*)pB;
            int4v hi = *(const int4v*)(pB + 16);
            b[j] = __builtin_shufflevector(lo, hi, 0, 1, 2, 3, 4, 5, 6, 7);
        }
        #pragma unroll
        for (int i = 0; i < 4; ++i)
            #pragma unroll
            for (int j = 0; j < 4; ++j)
                acc[i][j] = __builtin_amdgcn_mfma_scale_f32_16x16x128_f8f6f4(
                    a[i], b[j], acc[i][j], 0, 0,      // cbsz=0 (fp8), blgp=0 (fp8)
                    0, 0x7f7f7f7f, 0, 0x7f7f7f7f);    // unit E8M0 scales
        __syncthreads();
    }

    // ---- fused stage-2 epilogue: P[rb][col] += sum_h acc * ey(m,h) ----
    const int c  = row0 / CSTRIDE;   // block-uniform
    const int h0 = row0 - c * CSTRIDE;

    #pragma unroll
    for (int j = 0; j < 4; ++j) {
        const int jcol = wc * 64 + j * 16 + lr;
        const int m = (col0 + jcol) & (MM - 1);
        const float om0 = omega[m];
        float ss, sc;
        __sincosf(TWO_PI * om0, &ss, &sc);
        const float str = sc, sti = -ss;               // exp(-2pi i om0)
        float pr = 0.0f, pi = 0.0f;
        #pragma unroll
        for (int i = 0; i < 4; ++i) {
            const int hb = h0 + wr * 64 + i * 16 + lq * 4;
            float sn, cs;
            __sincosf(TWO_PI * om0 * (float)(hb - 150), &sn, &cs);
            float er = cs, ei = -sn;                   // ey at h = hb
            #pragma unroll
            for (int r = 0; r < 4; ++r) {
                const float v = acc[i][j][r];
                pr = fmaf(v, er, pr);
                pi = fmaf(v, ei, pi);
                float nr = er * str - ei * sti;
                ei = er * sti + ei * str;
                er = nr;
            }
        }
        // combine the 4 lq-lanes sharing this column (lanes lr, lr+16, lr+32, lr+48)
        pr += __shfl_down(pr, 32); pi += __shfl_down(pi, 32);
        pr += __shfl_down(pr, 16); pi += __shfl_down(pi, 16);
        if (lq == 0) {
            atomicAdd(&red[jcol].x, pr);               // 2-way contention (wr=0/1)
            atomicAdd(&red[jcol].y, pi);
        }
    }
    __syncthreads();

    if (t < 128) {
        const int rb = row0 >> 7;
        P[(size_t)rb * NP + col0 + t] = red[t];
    }
}

// loss: k[c,m] from 3 row-block partials (real cols at m, imag cols at m+4096)
__global__ __launch_bounds__(256) void loss_kernel(
    const float2* __restrict__ P, const float* __restrict__ kdata,
    const float* __restrict__ omega, float* __restrict__ out)
{
    const int t = blockIdx.x * 256 + threadIdx.x;  // 0..16383
    const int c = t >> 12;
    const int m = t & (MM - 1);

    float kr = 0.0f, ki = 0.0f;
    #pragma unroll
    for (int q = 0; q < 3; ++q) {
        const int rb = 3 * c + q;
        float2 p0 = P[(size_t)rb * NP + m];          // real-col partial
        float2 p1 = P[(size_t)rb * NP + m + MM];     // imag-col partial
        kr += p0.x - p1.y;
        ki += p0.y + p1.x;
    }
    kr *= (1.0f / 300.0f);
    ki *= (1.0f / 300.0f);

    const float om0 = omega[m];
    const float om1 = omega[MM + m];
    const size_t kidx = ((size_t)c * MM + m) * 2;
    const float kdr = kdata[kidx];
    const float kdi = kdata[kidx + 1];
    const float w0 = om0 * TWO_PI, w1 = om1 * TWO_PI;
    const float wg = sqrtf(w0 * w0 + w1 * w1) + 1.0f;
    const float dr = wg * (kr - kdr);
    const float di = wg * (ki - kdi);
    float val = (dr * dr + di * di) * (1.0f / (2.0f * CC * MM));

    #pragma unroll
    for (int off = 32; off > 0; off >>= 1) val += __shfl_down(val, off);
    if ((threadIdx.x & 63) == 0) atomicAdd(out, val);
}

extern "C" void kernel_launch(void* const* d_in, const int* in_sizes, int n_in,
                              void* d_out, int out_size, void* d_ws, size_t ws_size,
                              hipStream_t stream) {
    const float* img   = (const float*)d_in[0];   // (300,300,1)
    const float* kdata = (const float*)d_in[1];   // (1,4,4096,2)
    const float* omega = (const float*)d_in[2];   // (1,2,4096)
    const float* csm   = (const float*)d_in[4];   // (4,300,300,2)
    float* out = (float*)d_out;

    unsigned char* Aws = (unsigned char*)d_ws;                 // MP*KP  = 0.98 MB
    unsigned char* Bws = (unsigned char*)d_ws + (1u << 20);    // NP*KP  = 5.24 MB
    float2*        Pws = (float2*)((char*)d_ws + (8u << 20));  // NRB*NP*8 = 786 KB

    const int ablk = (MP * KP / 2) / 256;      // 1920
    const int bblk = (NP * KP / 2) / 256;      // 10240
    prep_kernel<<<ablk + bblk, 256, 0, stream>>>(img, csm, omega,
                                                 (ushort*)Aws, (ushort*)Bws, out);
    gemm_kernel<<<dim3(NP / 128, MP / 128), 256, 0, stream>>>(Aws, Bws, omega, Pws);
    loss_kernel<<<(CC * MM) / 256, 256, 0, stream>>>(Pws, kdata, omega, out);
}